// Round 1
// baseline (2524.827 us; speedup 1.0000x reference)
//
#include <hip/hip_runtime.h>
#include <hip/hip_bf16.h>
#include <cstdint>
#include <cstddef>

#define EMB   2048
#define NH    32
#define NG    8
#define DH    64
#define SEQ   2048
#define BB    2
#define MTOT  (BB*SEQ)   // 4096
#define NQT   (SEQ/64)   // 32

__device__ __forceinline__ float neg_inf() { return __int_as_float(0xff800000); }

// ---------- generic f32 GEMM: C[M,N] = A[M,K] @ W[K,N], M%64==N%64==K%16==0 ----------
__global__ __launch_bounds__(256)
void gemm_f32(const float* __restrict__ A, const float* __restrict__ W,
              float* __restrict__ C, int M, int N, int K) {
  __shared__ float As[16][68];   // [k][m], +4 pad keeps float4 alignment & kills conflicts
  __shared__ float Ws[16][68];   // [k][n]
  const int tid = threadIdx.x;
  const int tm = tid >> 4, tn = tid & 15;
  const int bm = blockIdx.y * 64, bn = blockIdx.x * 64;
  float acc[4][4] = {};
  for (int k0 = 0; k0 < K; k0 += 16) {
    {
      int r = tid >> 2;                 // 0..63
      int c = (tid & 3) << 2;           // 0,4,8,12
      float4 a4 = *(const float4*)(A + (size_t)(bm + r) * K + k0 + c);
      As[c+0][r] = a4.x; As[c+1][r] = a4.y; As[c+2][r] = a4.z; As[c+3][r] = a4.w;
    }
    {
      int r = tid >> 4;                 // 0..15
      int c = (tid & 15) << 2;          // 0..60
      *(float4*)&Ws[r][c] = *(const float4*)(W + (size_t)(k0 + r) * N + bn + c);
    }
    __syncthreads();
    #pragma unroll
    for (int kk = 0; kk < 16; ++kk) {
      float4 a4 = *(float4*)&As[kk][tm << 2];
      float4 w4 = *(float4*)&Ws[kk][tn << 2];
      float a[4] = {a4.x, a4.y, a4.z, a4.w};
      float w[4] = {w4.x, w4.y, w4.z, w4.w};
      #pragma unroll
      for (int i = 0; i < 4; ++i)
        #pragma unroll
        for (int j = 0; j < 4; ++j)
          acc[i][j] = fmaf(a[i], w[j], acc[i][j]);
    }
    __syncthreads();
  }
  #pragma unroll
  for (int i = 0; i < 4; ++i) {
    float4 o = make_float4(acc[i][0], acc[i][1], acc[i][2], acc[i][3]);
    *(float4*)(C + (size_t)(bm + (tm << 2) + i) * N + bn + (tn << 2)) = o;
  }
}

// ---------- fused RMSNorm (over D=64) + RoPE, in place; one wave per (row, head) ----------
__global__ __launch_bounds__(256)
void rmsnorm_rope(float* __restrict__ t, const float* __restrict__ scale,
                  const float* __restrict__ cs, const float* __restrict__ sn, int nh) {
  int wv   = (int)((blockIdx.x * 256 + threadIdx.x) >> 6);
  int lane = threadIdx.x & 63;
  int h = wv % nh;
  int m = wv / nh;
  if (m >= MTOT) return;
  int spos = m & (SEQ - 1);            // m = b*SEQ + s
  float* p = t + (size_t)m * (nh * DH) + h * DH;
  float val = p[lane];
  float sq = val * val;
  #pragma unroll
  for (int off = 32; off; off >>= 1) sq += __shfl_xor(sq, off);
  float r  = rsqrtf(sq * (1.0f / 64.0f) + 1e-6f);
  float xn = val * r * scale[lane];
  float partner = __shfl_xor(xn, 32);
  float c = cs[spos * DH + lane];
  float s = sn[spos * DH + lane];
  // rot = concat(-x2, x1): first half x*c - x2*s ; second half x*c + x1*s
  float out = (lane < 32) ? (xn * c - partner * s) : fmaf(xn, c, partner * s);
  p[lane] = out;
}

// ---------- causal flash attention, f32 ----------
// block = 256 threads = 4 waves; one block per (b, h, 64-row q-tile).
// Within a wave: 16 q-rows, 4 lanes per row (each owns 16 of the 64 dims).
__global__ __launch_bounds__(256)
void flash_f32(const float* __restrict__ qg, const float* __restrict__ kg,
               const float* __restrict__ vg, float* __restrict__ ctx) {
  __shared__ float Ks[64][64];
  __shared__ float Vs[64][64];
  const int bid = blockIdx.x;
  const int qt = bid % NQT;
  const int h  = (bid / NQT) % NH;
  const int b  = bid / (NQT * NH);
  const int g  = h >> 2;               // kv head (GS = 4)
  const int tid = threadIdx.x;
  const int w = tid >> 6, lane = tid & 63;
  const int rl = lane >> 2, part = lane & 3;
  const int qrow = qt * 64 + w * 16 + rl;

  const float* qp = qg + (size_t)(b * SEQ + qrow) * (NH * DH) + h * DH + part * 16;
  float qr[16];
  #pragma unroll
  for (int i = 0; i < 4; ++i) {
    float4 t4 = *(const float4*)(qp + 4 * i);
    qr[4*i+0] = t4.x * 0.125f; qr[4*i+1] = t4.y * 0.125f;   // 1/sqrt(64)
    qr[4*i+2] = t4.z * 0.125f; qr[4*i+3] = t4.w * 0.125f;
  }
  float acc[16] = {};
  float mrun = neg_inf(), lrun = 0.f;

  for (int kt = 0; kt <= qt; ++kt) {
    #pragma unroll
    for (int j = 0; j < 4; ++j) {       // cooperative K/V tile load (coalesced float4)
      int idx4 = tid + 256 * j;         // 0..1023
      int row = idx4 >> 4, c4 = (idx4 & 15) << 2;
      size_t off = (size_t)(b * SEQ + kt * 64 + row) * (NG * DH) + g * DH + c4;
      *(float4*)&Ks[row][c4] = *(const float4*)(kg + off);
      *(float4*)&Vs[row][c4] = *(const float4*)(vg + off);
    }
    __syncthreads();
    const int jmax = (kt == qt) ? (w * 16 + rl) : 63;  // keys kt*64+j valid iff j<=jmax
    for (int jc = 0; jc < 4; ++jc) {
      float sreg[16];
      #pragma unroll
      for (int jj = 0; jj < 16; ++jj) {
        int j = jc * 16 + jj;
        float ps = 0.f;
        #pragma unroll
        for (int i = 0; i < 4; ++i) {
          float4 kk = *(float4*)&Ks[j][part * 16 + 4 * i];
          ps = fmaf(qr[4*i+0], kk.x, ps);
          ps = fmaf(qr[4*i+1], kk.y, ps);
          ps = fmaf(qr[4*i+2], kk.z, ps);
          ps = fmaf(qr[4*i+3], kk.w, ps);
        }
        ps += __shfl_xor(ps, 1);        // reduce the 4 partial dots per row
        ps += __shfl_xor(ps, 2);
        sreg[jj] = (j <= jmax) ? ps : neg_inf();
      }
      float tmax = mrun;
      #pragma unroll
      for (int jj = 0; jj < 16; ++jj) tmax = fmaxf(tmax, sreg[jj]);
      if (tmax == neg_inf()) continue;  // fully-masked chunk before any valid key
      float rescale = __expf(mrun - tmax);   // mrun=-inf -> 0
      mrun = tmax;
      lrun *= rescale;
      #pragma unroll
      for (int d = 0; d < 16; ++d) acc[d] *= rescale;
      float p[16]; float psum = 0.f;
      #pragma unroll
      for (int jj = 0; jj < 16; ++jj) { p[jj] = __expf(sreg[jj] - mrun); psum += p[jj]; }
      lrun += psum;
      #pragma unroll
      for (int jj = 0; jj < 16; ++jj) {
        float pv = p[jj];
        #pragma unroll
        for (int i = 0; i < 4; ++i) {
          float4 vv = *(float4*)&Vs[jc * 16 + jj][part * 16 + 4 * i];
          acc[4*i+0] = fmaf(pv, vv.x, acc[4*i+0]);
          acc[4*i+1] = fmaf(pv, vv.y, acc[4*i+1]);
          acc[4*i+2] = fmaf(pv, vv.z, acc[4*i+2]);
          acc[4*i+3] = fmaf(pv, vv.w, acc[4*i+3]);
        }
      }
    }
    __syncthreads();
  }
  const float inv = 1.0f / lrun;
  float* op = ctx + (size_t)(b * SEQ + qrow) * (NH * DH) + h * DH + part * 16;
  #pragma unroll
  for (int i = 0; i < 4; ++i) {
    float4 o = make_float4(acc[4*i+0]*inv, acc[4*i+1]*inv, acc[4*i+2]*inv, acc[4*i+3]*inv);
    *(float4*)(op + 4 * i) = o;
  }
}

extern "C" void kernel_launch(void* const* d_in, const int* in_sizes, int n_in,
                              void* d_out, int out_size, void* d_ws, size_t ws_size,
                              hipStream_t stream) {
  const float* x  = (const float*)d_in[0];
  // d_in[1] = mask (bool, unused: causal triu(k=1) is known analytically)
  const float* cs = (const float*)d_in[2];
  const float* sn = (const float*)d_in[3];
  const float* Wq = (const float*)d_in[4];
  const float* Wk = (const float*)d_in[5];
  const float* Wv = (const float*)d_in[6];
  const float* Wo = (const float*)d_in[7];
  const float* qs = (const float*)d_in[8];
  const float* ks = (const float*)d_in[9];
  float* out = (float*)d_out;

  // workspace layout (f32): q[4096][2048] | k[4096][512] | v[4096][512] | ctx[4096][2048]
  float* qw = (float*)d_ws;
  float* kw = qw + (size_t)MTOT * NH * DH;
  float* vw = kw + (size_t)MTOT * NG * DH;
  float* cw = vw + (size_t)MTOT * NG * DH;   // total 80 MiB

  dim3 blk(256);
  gemm_f32<<<dim3(2048/64, MTOT/64), blk, 0, stream>>>(x,  Wq, qw, MTOT, 2048, EMB);
  gemm_f32<<<dim3(512/64,  MTOT/64), blk, 0, stream>>>(x,  Wk, kw, MTOT, 512,  EMB);
  gemm_f32<<<dim3(512/64,  MTOT/64), blk, 0, stream>>>(x,  Wv, vw, MTOT, 512,  EMB);
  rmsnorm_rope<<<dim3(MTOT * NH / 4), blk, 0, stream>>>(qw, qs, cs, sn, NH);
  rmsnorm_rope<<<dim3(MTOT * NG / 4), blk, 0, stream>>>(kw, ks, cs, sn, NG);
  flash_f32<<<dim3(BB * NH * NQT), blk, 0, stream>>>(qw, kw, vw, cw);
  gemm_f32<<<dim3(2048/64, MTOT/64), blk, 0, stream>>>(cw, Wo, out, MTOT, 2048, EMB);
}

// Round 2
// 352.740 us; speedup vs baseline: 7.1578x; 7.1578x over previous
//
#include <hip/hip_runtime.h>
#include <hip/hip_bf16.h>
#include <cstdint>
#include <cstddef>

#define EMB   2048
#define NH_   32
#define NG_   8
#define DH_   64
#define SEQ_  2048
#define BB_   2
#define MTOT  4096
#define LDQKV 3072

typedef __attribute__((ext_vector_type(8))) short s16x8;
typedef __attribute__((ext_vector_type(8))) unsigned short u16x8;
typedef __attribute__((ext_vector_type(4))) float f32x4;

__device__ __forceinline__ float bf2f(unsigned short u) {
  unsigned int x = (unsigned int)u << 16; return __uint_as_float(x);
}
__device__ __forceinline__ unsigned short f2bf(float f) {
  unsigned int x = __float_as_uint(f);
  x = x + 0x7FFFu + ((x >> 16) & 1u);          // RNE
  return (unsigned short)(x >> 16);
}
__device__ __forceinline__ float ninf() { return __int_as_float(0xff800000); }

__device__ __forceinline__ void glds16(const void* g, void* l) {
  __builtin_amdgcn_global_load_lds((const __attribute__((address_space(1))) void*)g,
                                   (__attribute__((address_space(3))) void*)l, 16, 0, 0);
}

// ---------- x f32 -> bf16 ----------
__global__ __launch_bounds__(256)
void cvtx(const float* __restrict__ x, unsigned short* __restrict__ xb) {
  size_t i = (size_t)blockIdx.x * 256 + threadIdx.x;   // 1,048,576 total, 8 elems each
  float4 a = *(const float4*)(x + i * 8);
  float4 c = *(const float4*)(x + i * 8 + 4);
  u16x8 o;
  o[0] = f2bf(a.x); o[1] = f2bf(a.y); o[2] = f2bf(a.z); o[3] = f2bf(a.w);
  o[4] = f2bf(c.x); o[5] = f2bf(c.y); o[6] = f2bf(c.z); o[7] = f2bf(c.w);
  *(u16x8*)(xb + i * 8) = o;
}

// ---------- W[K=2048][N] f32 -> Wt[N][2048] bf16 ----------
__global__ __launch_bounds__(256)
void wtrans(const float* __restrict__ in, unsigned short* __restrict__ out, int N) {
  __shared__ float tile[64][65];
  const int tid = threadIdx.x;
  const int n0 = blockIdx.x * 64, k0 = blockIdx.y * 64;
  #pragma unroll
  for (int jj = 0; jj < 4; ++jj) {
    int r = (tid >> 4) + jj * 16;
    int c = (tid & 15) * 4;
    float4 v = *(const float4*)(in + (size_t)(k0 + r) * N + n0 + c);
    tile[r][c] = v.x; tile[r][c + 1] = v.y; tile[r][c + 2] = v.z; tile[r][c + 3] = v.w;
  }
  __syncthreads();
  #pragma unroll
  for (int rep = 0; rep < 2; ++rep) {
    int u = rep * 256 + tid;
    int nl = u >> 3, ch = u & 7;
    u16x8 o;
    #pragma unroll
    for (int e = 0; e < 8; ++e) o[e] = f2bf(tile[ch * 8 + e][nl]);
    *(u16x8*)(out + (size_t)(n0 + nl) * 2048 + k0 + ch * 8) = o;
  }
}

// ---------- MFMA GEMM: C[M,N] = A[M,2048] @ Bt[N,2048]^T ; BM=BN=128, BK=32 ----------
template<int BF16OUT>
__global__ __launch_bounds__(256)
void gemm_bt(const unsigned short* __restrict__ A, const unsigned short* __restrict__ Bt,
             void* __restrict__ C, int ldc) {
  __shared__ __align__(16) unsigned short As[128 * 32];
  __shared__ __align__(16) unsigned short Bs[128 * 32];
  const int tid = threadIdx.x;
  const int w = tid >> 6, lane = tid & 63;
  const int grp = lane >> 4, l15 = lane & 15;
  const int wr = w >> 1, wc = w & 1;
  const int bm = blockIdx.y * 128, bn = blockIdx.x * 128;
  f32x4 acc[4][4] = {};
  for (int k0 = 0; k0 < 2048; k0 += 32) {
    #pragma unroll
    for (int j = 0; j < 2; ++j) {
      int unit = (j * 4 + w) * 64 + lane;     // 0..511, 16B each
      int row = unit >> 2, ch = unit & 3;
      glds16(A  + (size_t)(bm + row) * 2048 + k0 + ch * 8, (char*)As + (j * 4 + w) * 1024);
      glds16(Bt + (size_t)(bn + row) * 2048 + k0 + ch * 8, (char*)Bs + (j * 4 + w) * 1024);
    }
    __syncthreads();
    s16x8 af[4], bf[4];
    #pragma unroll
    for (int i = 0; i < 4; ++i)
      af[i] = *(const s16x8*)((const char*)As + (wr * 64 + i * 16 + l15) * 64 + grp * 16);
    #pragma unroll
    for (int j = 0; j < 4; ++j)
      bf[j] = *(const s16x8*)((const char*)Bs + (wc * 64 + j * 16 + l15) * 64 + grp * 16);
    #pragma unroll
    for (int i = 0; i < 4; ++i)
      #pragma unroll
      for (int j = 0; j < 4; ++j)
        acc[i][j] = __builtin_amdgcn_mfma_f32_16x16x32_bf16(af[i], bf[j], acc[i][j], 0, 0, 0);
    __syncthreads();
  }
  #pragma unroll
  for (int i = 0; i < 4; ++i)
    #pragma unroll
    for (int j = 0; j < 4; ++j)
      #pragma unroll
      for (int r = 0; r < 4; ++r) {
        int row = bm + wr * 64 + i * 16 + grp * 4 + r;
        int col = bn + wc * 64 + j * 16 + l15;
        float v = acc[i][j][r];
        if (BF16OUT) ((unsigned short*)C)[(size_t)row * ldc + col] = f2bf(v);
        else         ((float*)C)[(size_t)row * ldc + col] = v;
      }
}

// ---------- fused RMSNorm(D=64) + RoPE, in-place bf16; one wave per (row, head) ----------
__global__ __launch_bounds__(256)
void rmsrope(unsigned short* __restrict__ t, const float* __restrict__ scale,
             const float* __restrict__ cs, const float* __restrict__ sn, int coff) {
  int m = blockIdx.x * 4 + (threadIdx.x >> 6);
  int h = blockIdx.y;
  int lane = threadIdx.x & 63;
  int spos = m & (SEQ_ - 1);
  unsigned short* p = t + (size_t)m * LDQKV + coff + h * 64 + lane;
  float val = bf2f(*p);
  float sq = val * val;
  #pragma unroll
  for (int off = 32; off; off >>= 1) sq += __shfl_xor(sq, off);
  float r = rsqrtf(sq * (1.f / 64.f) + 1e-6f);
  float xn = val * r * scale[lane];
  float partner = __shfl_xor(xn, 32);
  float c = cs[spos * 64 + lane], s = sn[spos * 64 + lane];
  float o = (lane < 32) ? (xn * c - partner * s) : fmaf(xn, c, partner * s);
  *p = f2bf(o);
}

// ---------- v region of qkv -> vT[(b*8+g)*64 + d][s] bf16 ----------
__global__ __launch_bounds__(256)
void vtrans(const unsigned short* __restrict__ qkv, unsigned short* __restrict__ vT) {
  __shared__ unsigned short tile[64][72];
  const int tid = threadIdx.x;
  const int st = blockIdx.x;             // s tile 0..31
  const int bg = blockIdx.y;             // 0..15
  const int b = bg >> 3, g = bg & 7;
  #pragma unroll
  for (int rep = 0; rep < 2; ++rep) {
    int u = rep * 256 + tid;
    int sl = u >> 3, ch = u & 7;
    u16x8 v = *(const u16x8*)(qkv + (size_t)(b * SEQ_ + st * 64 + sl) * LDQKV + 2560 + g * 64 + ch * 8);
    #pragma unroll
    for (int e = 0; e < 8; ++e) tile[sl][ch * 8 + e] = v[e];
  }
  __syncthreads();
  #pragma unroll
  for (int rep = 0; rep < 2; ++rep) {
    int u = rep * 256 + tid;
    int d = u >> 3, ch = u & 7;
    u16x8 o;
    #pragma unroll
    for (int e = 0; e < 8; ++e) o[e] = tile[ch * 8 + e][d];
    *(u16x8*)(vT + (size_t)(bg * 64 + d) * SEQ_ + st * 64 + ch * 8) = o;
  }
}

// ---------- MFMA flash attention ----------
// block = 4 waves; QBLK=128 (32 q-rows/wave = 2 q-frags), KVBLK=64.
// S^T = mfma(K, Q): softmax state lives at q = lane&15 (local reduce + 2 shfl).
// P staged via XOR-swizzled LDS; V from pre-transposed vT.
#define SM_C 0.18033688f   // 0.125 * log2(e)
__global__ __launch_bounds__(256)
void attn_mfma(const unsigned short* __restrict__ qkv, const unsigned short* __restrict__ vT,
               unsigned short* __restrict__ ctx) {
  __shared__ __align__(16) unsigned short Ks[64 * 64];
  __shared__ __align__(16) unsigned short Vs[64 * 64];
  __shared__ __align__(16) unsigned short Ps[4 * 16 * 64];
  const int tid = threadIdx.x;
  const int w = tid >> 6, lane = tid & 63;
  const int grp = lane >> 4, l15 = lane & 15;
  const int bid = blockIdx.x;
  const int qb = 15 - (bid & 15);                 // big q-tiles first (load balance)
  const int h = (bid >> 4) & 31;
  const int b = bid >> 9;
  const int g = h >> 2;
  const int qbase = qb * 128 + w * 32;
  char* Pw = (char*)Ps + w * 2048;
  const int swz = (l15 & 7) << 4;

  s16x8 qf[2][2];
  #pragma unroll
  for (int f = 0; f < 2; ++f)
    #pragma unroll
    for (int s = 0; s < 2; ++s)
      qf[f][s] = *(const s16x8*)(qkv + (size_t)(b * SEQ_ + qbase + f * 16 + l15) * LDQKV
                                 + h * 64 + s * 32 + grp * 8);

  f32x4 acc[2][4] = {};
  float m_st[2] = {ninf(), ninf()};
  float l_st[2] = {0.f, 0.f};
  const int nkt = (qb + 1) * 2;

  for (int kt = 0; kt < nkt; ++kt) {
    const int kbase = kt * 64;
    #pragma unroll
    for (int j = 0; j < 2; ++j) {                 // stage K + vT tiles (swizzled source)
      int unit = (j * 4 + w) * 64 + lane;         // 0..511
      int row = unit >> 3, ch = unit & 7;
      int sch = ch ^ (row & 7);
      glds16(qkv + (size_t)(b * SEQ_ + kbase + row) * LDQKV + 2048 + g * 64 + sch * 8,
             (char*)Ks + (j * 4 + w) * 1024);
      glds16(vT + (size_t)((b * NG_ + g) * 64 + row) * SEQ_ + kbase + sch * 8,
             (char*)Vs + (j * 4 + w) * 1024);
    }
    __syncthreads();
    if (kbase <= qbase + 31) {                    // wave has at least one unmasked pair
      const bool diag = (kbase + 63 > qbase);
      s16x8 kfr[4][2], vfr[4][2];
      #pragma unroll
      for (int kf = 0; kf < 4; ++kf)
        #pragma unroll
        for (int s = 0; s < 2; ++s) {
          int row = kf * 16 + l15;
          kfr[kf][s] = *(const s16x8*)((const char*)Ks + row * 128 + (((s * 4 + grp) ^ (row & 7)) * 16));
        }
      #pragma unroll
      for (int dn = 0; dn < 4; ++dn)
        #pragma unroll
        for (int s = 0; s < 2; ++s) {
          int row = dn * 16 + l15;
          vfr[dn][s] = *(const s16x8*)((const char*)Vs + row * 128 + (((s * 4 + grp) ^ (row & 7)) * 16));
        }
      #pragma unroll
      for (int f = 0; f < 2; ++f) {
        f32x4 st[4];
        #pragma unroll
        for (int kf = 0; kf < 4; ++kf) {
          f32x4 c0 = {0.f, 0.f, 0.f, 0.f};
          c0 = __builtin_amdgcn_mfma_f32_16x16x32_bf16(kfr[kf][0], qf[f][0], c0, 0, 0, 0);
          c0 = __builtin_amdgcn_mfma_f32_16x16x32_bf16(kfr[kf][1], qf[f][1], c0, 0, 0, 0);
          st[kf] = c0;
        }
        const int qabs = qbase + f * 16 + l15;
        if (diag) {
          #pragma unroll
          for (int kf = 0; kf < 4; ++kf)
            #pragma unroll
            for (int r = 0; r < 4; ++r)
              if (kbase + kf * 16 + grp * 4 + r > qabs) st[kf][r] = ninf();
        }
        float pm = st[0][0];
        #pragma unroll
        for (int kf = 0; kf < 4; ++kf)
          #pragma unroll
          for (int r = 0; r < 4; ++r) pm = fmaxf(pm, st[kf][r]);
        pm = fmaxf(pm, __shfl_xor(pm, 16));
        pm = fmaxf(pm, __shfl_xor(pm, 32));
        const float mnew = fmaxf(m_st[f], pm);
        float psum = 0.f;
        #pragma unroll
        for (int kf = 0; kf < 4; ++kf) {
          float p0 = exp2f((st[kf][0] - mnew) * SM_C);
          float p1 = exp2f((st[kf][1] - mnew) * SM_C);
          float p2 = exp2f((st[kf][2] - mnew) * SM_C);
          float p3 = exp2f((st[kf][3] - mnew) * SM_C);
          psum += (p0 + p1) + (p2 + p3);
          unsigned int w0 = (unsigned int)f2bf(p0) | ((unsigned int)f2bf(p1) << 16);
          unsigned int w1 = (unsigned int)f2bf(p2) | ((unsigned int)f2bf(p3) << 16);
          int byte0 = l15 * 128 + kf * 32 + grp * 8;
          *(unsigned int*)(Pw + (byte0 ^ swz)) = w0;
          *(unsigned int*)(Pw + ((byte0 + 4) ^ swz)) = w1;
        }
        psum += __shfl_xor(psum, 16);
        psum += __shfl_xor(psum, 32);
        const float fac = exp2f((m_st[f] - mnew) * SM_C);
        l_st[f] = l_st[f] * fac + psum;
        m_st[f] = mnew;
        float fr[4];
        #pragma unroll
        for (int r = 0; r < 4; ++r) fr[r] = __shfl(fac, grp * 4 + r);
        #pragma unroll
        for (int dn = 0; dn < 4; ++dn)
          #pragma unroll
          for (int r = 0; r < 4; ++r) acc[f][dn][r] *= fr[r];
        #pragma unroll
        for (int ks = 0; ks < 2; ++ks) {
          s16x8 pa = *(const s16x8*)(Pw + ((l15 * 128 + ks * 64 + grp * 16) ^ swz));
          #pragma unroll
          for (int dn = 0; dn < 4; ++dn)
            acc[f][dn] = __builtin_amdgcn_mfma_f32_16x16x32_bf16(pa, vfr[dn][ks], acc[f][dn], 0, 0, 0);
        }
      }
    }
    __syncthreads();
  }
  #pragma unroll
  for (int f = 0; f < 2; ++f) {
    float linv[4];
    #pragma unroll
    for (int r = 0; r < 4; ++r) linv[r] = 1.f / __shfl(l_st[f], grp * 4 + r);
    #pragma unroll
    for (int dn = 0; dn < 4; ++dn)
      #pragma unroll
      for (int r = 0; r < 4; ++r) {
        int row = b * SEQ_ + qbase + f * 16 + grp * 4 + r;
        ctx[(size_t)row * 2048 + h * 64 + dn * 16 + l15] = f2bf(acc[f][dn][r] * linv[r]);
      }
  }
}

extern "C" void kernel_launch(void* const* d_in, const int* in_sizes, int n_in,
                              void* d_out, int out_size, void* d_ws, size_t ws_size,
                              hipStream_t stream) {
  const float* x  = (const float*)d_in[0];
  // d_in[1] = mask (causal, analytic)
  const float* cs = (const float*)d_in[2];
  const float* sn = (const float*)d_in[3];
  const float* Wq = (const float*)d_in[4];
  const float* Wk = (const float*)d_in[5];
  const float* Wv = (const float*)d_in[6];
  const float* Wo = (const float*)d_in[7];
  const float* qs = (const float*)d_in[8];
  const float* ks = (const float*)d_in[9];
  float* out = (float*)d_out;

  // ws (bf16): xb[4096][2048] | Wt[3072][2048] | Wot[2048][2048] | qkv[4096][3072]
  //            | vT[16*64][2048] | ctx[4096][2048]   == 80 MiB
  unsigned short* xb  = (unsigned short*)d_ws;
  unsigned short* Wt  = xb  + (size_t)4096 * 2048;
  unsigned short* Wot = Wt  + (size_t)3072 * 2048;
  unsigned short* qkv = Wot + (size_t)2048 * 2048;
  unsigned short* vTb = qkv + (size_t)4096 * 3072;
  unsigned short* ctx = vTb + (size_t)16 * 64 * 2048;

  cvtx<<<4096, 256, 0, stream>>>(x, xb);
  wtrans<<<dim3(32, 32), 256, 0, stream>>>(Wq, Wt, 2048);
  wtrans<<<dim3(8, 32),  256, 0, stream>>>(Wk, Wt + (size_t)2048 * 2048, 512);
  wtrans<<<dim3(8, 32),  256, 0, stream>>>(Wv, Wt + (size_t)2560 * 2048, 512);
  wtrans<<<dim3(32, 32), 256, 0, stream>>>(Wo, Wot, 2048);
  gemm_bt<1><<<dim3(24, 32), 256, 0, stream>>>(xb, Wt, qkv, 3072);
  rmsrope<<<dim3(1024, 32), 256, 0, stream>>>(qkv, qs, cs, sn, 0);
  rmsrope<<<dim3(1024, 8),  256, 0, stream>>>(qkv, ks, cs, sn, 2048);
  vtrans<<<dim3(32, 16), 256, 0, stream>>>(qkv, vTb);
  attn_mfma<<<1024, 256, 0, stream>>>(qkv, vTb, ctx);
  gemm_bt<0><<<dim3(16, 32), 256, 0, stream>>>(ctx, Wot, out, 2048);
}

// Round 4
// 323.490 us; speedup vs baseline: 7.8050x; 1.0904x over previous
//
#include <hip/hip_runtime.h>
#include <hip/hip_bf16.h>
#include <cstdint>
#include <cstddef>

#define EMB   2048
#define NH_   32
#define NG_   8
#define DH_   64
#define SEQ_  2048
#define BB_   2
#define MTOT  4096
#define LDQKV 3072

typedef __attribute__((ext_vector_type(8))) short s16x8;
typedef __attribute__((ext_vector_type(8))) unsigned short u16x8;
typedef __attribute__((ext_vector_type(4))) float f32x4;
typedef __attribute__((ext_vector_type(4))) unsigned int u32x4;

__device__ __forceinline__ float bf2f(unsigned short u) {
  unsigned int x = (unsigned int)u << 16; return __uint_as_float(x);
}
__device__ __forceinline__ unsigned short f2bf(float f) {
  unsigned int x = __float_as_uint(f);
  x = x + 0x7FFFu + ((x >> 16) & 1u);          // RNE
  return (unsigned short)(x >> 16);
}
__device__ __forceinline__ float ninf() { return __int_as_float(0xff800000); }
__device__ __forceinline__ unsigned int pack_bf2(float a, float b) {
  unsigned int r;
  asm("v_cvt_pk_bf16_f32 %0, %1, %2" : "=v"(r) : "v"(a), "v"(b));
  return r;
}

__device__ __forceinline__ void glds16(const void* g, void* l) {
  __builtin_amdgcn_global_load_lds((const __attribute__((address_space(1))) void*)g,
                                   (__attribute__((address_space(3))) void*)l, 16, 0, 0);
}

// ---------- x f32 -> bf16 ----------
__global__ __launch_bounds__(256)
void cvtx(const float* __restrict__ x, unsigned short* __restrict__ xb) {
  size_t i = (size_t)blockIdx.x * 256 + threadIdx.x;
  float4 a = *(const float4*)(x + i * 8);
  float4 c = *(const float4*)(x + i * 8 + 4);
  u16x8 o;
  o[0] = f2bf(a.x); o[1] = f2bf(a.y); o[2] = f2bf(a.z); o[3] = f2bf(a.w);
  o[4] = f2bf(c.x); o[5] = f2bf(c.y); o[6] = f2bf(c.z); o[7] = f2bf(c.w);
  *(u16x8*)(xb + i * 8) = o;
}

// ---------- W[K=2048][N] f32 -> Wt[N][2048] bf16 ----------
__global__ __launch_bounds__(256)
void wtrans(const float* __restrict__ in, unsigned short* __restrict__ out, int N) {
  __shared__ float tile[64][65];
  const int tid = threadIdx.x;
  const int n0 = blockIdx.x * 64, k0 = blockIdx.y * 64;
  #pragma unroll
  for (int jj = 0; jj < 4; ++jj) {
    int r = (tid >> 4) + jj * 16;
    int c = (tid & 15) * 4;
    float4 v = *(const float4*)(in + (size_t)(k0 + r) * N + n0 + c);
    tile[r][c] = v.x; tile[r][c + 1] = v.y; tile[r][c + 2] = v.z; tile[r][c + 3] = v.w;
  }
  __syncthreads();
  #pragma unroll
  for (int rep = 0; rep < 2; ++rep) {
    int u = rep * 256 + tid;
    int nl = u >> 3, ch = u & 7;
    u16x8 o;
    #pragma unroll
    for (int e = 0; e < 8; ++e) o[e] = f2bf(tile[ch * 8 + e][nl]);
    *(u16x8*)(out + (size_t)(n0 + nl) * 2048 + k0 + ch * 8) = o;
  }
}

// ---------- MFMA GEMM: C[M,N] = A[M,2048] @ Bt[N,2048]^T ; BM=BN=128, BK=32 ----------
template<int BF16OUT>
__global__ __launch_bounds__(256)
void gemm_bt(const unsigned short* __restrict__ A, const unsigned short* __restrict__ Bt,
             void* __restrict__ C, int ldc) {
  __shared__ __align__(16) unsigned short As[128 * 32];
  __shared__ __align__(16) unsigned short Bs[128 * 32];
  const int tid = threadIdx.x;
  const int w = tid >> 6, lane = tid & 63;
  const int grp = lane >> 4, l15 = lane & 15;
  const int wr = w >> 1, wc = w & 1;
  const int bm = blockIdx.y * 128, bn = blockIdx.x * 128;
  f32x4 acc[4][4] = {};
  for (int k0 = 0; k0 < 2048; k0 += 32) {
    #pragma unroll
    for (int j = 0; j < 2; ++j) {
      int unit = (j * 4 + w) * 64 + lane;
      int row = unit >> 2, ch = unit & 3;
      glds16(A  + (size_t)(bm + row) * 2048 + k0 + ch * 8, (char*)As + (j * 4 + w) * 1024);
      glds16(Bt + (size_t)(bn + row) * 2048 + k0 + ch * 8, (char*)Bs + (j * 4 + w) * 1024);
    }
    __syncthreads();
    s16x8 af[4], bf[4];
    #pragma unroll
    for (int i = 0; i < 4; ++i)
      af[i] = *(const s16x8*)((const char*)As + (wr * 64 + i * 16 + l15) * 64 + grp * 16);
    #pragma unroll
    for (int j = 0; j < 4; ++j)
      bf[j] = *(const s16x8*)((const char*)Bs + (wc * 64 + j * 16 + l15) * 64 + grp * 16);
    #pragma unroll
    for (int i = 0; i < 4; ++i)
      #pragma unroll
      for (int j = 0; j < 4; ++j)
        acc[i][j] = __builtin_amdgcn_mfma_f32_16x16x32_bf16(af[i], bf[j], acc[i][j], 0, 0, 0);
    __syncthreads();
  }
  #pragma unroll
  for (int i = 0; i < 4; ++i)
    #pragma unroll
    for (int j = 0; j < 4; ++j)
      #pragma unroll
      for (int r = 0; r < 4; ++r) {
        int row = bm + wr * 64 + i * 16 + grp * 4 + r;
        int col = bn + wc * 64 + j * 16 + l15;
        float v = acc[i][j][r];
        if (BF16OUT) ((unsigned short*)C)[(size_t)row * ldc + col] = f2bf(v);
        else         ((float*)C)[(size_t)row * ldc + col] = v;
      }
}

// ---------- fused RMSNorm(D=64) + RoPE, in-place bf16 ----------
__global__ __launch_bounds__(256)
void rmsrope(unsigned short* __restrict__ t, const float* __restrict__ scale,
             const float* __restrict__ cs, const float* __restrict__ sn, int coff) {
  int m = blockIdx.x * 4 + (threadIdx.x >> 6);
  int h = blockIdx.y;
  int lane = threadIdx.x & 63;
  int spos = m & (SEQ_ - 1);
  unsigned short* p = t + (size_t)m * LDQKV + coff + h * 64 + lane;
  float val = bf2f(*p);
  float sq = val * val;
  #pragma unroll
  for (int off = 32; off; off >>= 1) sq += __shfl_xor(sq, off);
  float r = rsqrtf(sq * (1.f / 64.f) + 1e-6f);
  float xn = val * r * scale[lane];
  float partner = __shfl_xor(xn, 32);
  float c = cs[spos * 64 + lane], s = sn[spos * 64 + lane];
  float o = (lane < 32) ? (xn * c - partner * s) : fmaf(xn, c, partner * s);
  *p = f2bf(o);
}

// ---------- v region of qkv -> vT[(b*8+g)*64 + d][s] bf16 ----------
__global__ __launch_bounds__(256)
void vtrans(const unsigned short* __restrict__ qkv, unsigned short* __restrict__ vT) {
  __shared__ unsigned short tile[64][72];
  const int tid = threadIdx.x;
  const int st = blockIdx.x;
  const int bg = blockIdx.y;
  const int b = bg >> 3, g = bg & 7;
  #pragma unroll
  for (int rep = 0; rep < 2; ++rep) {
    int u = rep * 256 + tid;
    int sl = u >> 3, ch = u & 7;
    u16x8 v = *(const u16x8*)(qkv + (size_t)(b * SEQ_ + st * 64 + sl) * LDQKV + 2560 + g * 64 + ch * 8);
    #pragma unroll
    for (int e = 0; e < 8; ++e) tile[sl][ch * 8 + e] = v[e];
  }
  __syncthreads();
  #pragma unroll
  for (int rep = 0; rep < 2; ++rep) {
    int u = rep * 256 + tid;
    int d = u >> 3, ch = u & 7;
    u16x8 o;
    #pragma unroll
    for (int e = 0; e < 8; ++e) o[e] = tile[ch * 8 + e][d];
    *(u16x8*)(vT + (size_t)(bg * 64 + d) * SEQ_ + st * 64 + ch * 8) = o;
  }
}

// ---------- MFMA flash attention v2: barrier-free, LDS-free ----------
// One wave owns 32 q-rows (2 16-row frags). K/V frags read straight from
// global (L2-resident: K/V per (b,g) = 512 KB). S^T = mfma(K,Q) puts softmax
// rows at l15; P redistributed to the PV A-fragment via cvt_pk + 8 bpermute.
// Block's 4 waves take q-tiles {63-i, i, 32+i, 31-i}: constant 130 kt/block.
__global__ __launch_bounds__(256)
void attn_mfma2(const unsigned short* __restrict__ qkv, const unsigned short* __restrict__ vT,
                unsigned short* __restrict__ ctx) {
  const int tid = threadIdx.x;
  const int w = tid >> 6, lane = tid & 63;
  const int grp = lane >> 4, l15 = lane & 15;
  const int bid = blockIdx.x;
  const int hs = bid >> 4, i = bid & 15;
  const int b = hs >> 5, h = hs & 31, g = h >> 2;
  const int qt = (w == 0) ? (63 - i) : (w == 1) ? i : (w == 2) ? (32 + i) : (31 - i);
  const int qbase = qt * 32;
  const int nkt = qt + 1;

  // Q fragments (B-operand: n = q = l15, k = d)
  s16x8 qf[2][2];
  #pragma unroll
  for (int f = 0; f < 2; ++f)
    #pragma unroll
    for (int s = 0; s < 2; ++s)
      qf[f][s] = *(const s16x8*)(qkv + (size_t)(b * SEQ_ + qbase + f * 16 + l15) * LDQKV
                                 + h * 64 + s * 32 + grp * 8);

  // per-lane base pointers
  const unsigned short* kp = qkv + (size_t)(b * SEQ_ + l15) * LDQKV + 2048 + g * 64 + grp * 8;
  const unsigned short* vp = vT + (size_t)((b * NG_ + g) * 64 + l15) * SEQ_ + grp * 8;

  f32x4 acc[2][4] = {};
  float m_st[2] = {ninf(), ninf()};
  float l_st[2] = {0.f, 0.f};

  const int srcA = ((grp & 1) << 5) | l15;   // lane holding sgrp = 2*(grp&1)
  const int srcB = srcA + 16;                // sgrp = 2*(grp&1)+1

#define LOADK(KF, KB) do {                                          \
    const unsigned short* kq_ = kp + (size_t)(KB) * LDQKV;          \
    KF[0][0] = *(const s16x8*)(kq_);                                \
    KF[0][1] = *(const s16x8*)(kq_ + 32);                           \
    KF[1][0] = *(const s16x8*)(kq_ + 16 * LDQKV);                   \
    KF[1][1] = *(const s16x8*)(kq_ + 16 * LDQKV + 32);              \
  } while (0)

  s16x8 kA[2][2], kB[2][2];
  LOADK(kA, 0);

  auto body = [&](const s16x8 (&KF)[2][2], int kt_) {
    const int kbase = kt_ * 32;
    const bool diag = (kt_ == qt);
    s16x8 vfr[4];
    {
      const unsigned short* vq = vp + kbase;
      vfr[0] = *(const s16x8*)(vq);
      vfr[1] = *(const s16x8*)(vq + 16 * SEQ_);
      vfr[2] = *(const s16x8*)(vq + 32 * SEQ_);
      vfr[3] = *(const s16x8*)(vq + 48 * SEQ_);
    }
    #pragma unroll
    for (int f = 0; f < 2; ++f) {
      f32x4 st0 = {0.f, 0.f, 0.f, 0.f}, st1 = {0.f, 0.f, 0.f, 0.f};
      st0 = __builtin_amdgcn_mfma_f32_16x16x32_bf16(KF[0][0], qf[f][0], st0, 0, 0, 0);
      st0 = __builtin_amdgcn_mfma_f32_16x16x32_bf16(KF[0][1], qf[f][1], st0, 0, 0, 0);
      st1 = __builtin_amdgcn_mfma_f32_16x16x32_bf16(KF[1][0], qf[f][0], st1, 0, 0, 0);
      st1 = __builtin_amdgcn_mfma_f32_16x16x32_bf16(KF[1][1], qf[f][1], st1, 0, 0, 0);
      if (diag) {                         // mask k > q on the diagonal tile
        const int qloc = f * 16 + l15;
        #pragma unroll
        for (int r = 0; r < 4; ++r) {
          if (grp * 4 + r > qloc)      st0[r] = ninf();
          if (16 + grp * 4 + r > qloc) st1[r] = ninf();
        }
      }
      float pm = fmaxf(fmaxf(fmaxf(st0[0], st0[1]), fmaxf(st0[2], st0[3])),
                       fmaxf(fmaxf(st1[0], st1[1]), fmaxf(st1[2], st1[3])));
      pm = fmaxf(pm, __shfl_xor(pm, 16));
      pm = fmaxf(pm, __shfl_xor(pm, 32));
      const float mnew = fmaxf(m_st[f], pm);
      float p00 = __expf((st0[0] - mnew) * 0.125f);
      float p01 = __expf((st0[1] - mnew) * 0.125f);
      float p02 = __expf((st0[2] - mnew) * 0.125f);
      float p03 = __expf((st0[3] - mnew) * 0.125f);
      float p10 = __expf((st1[0] - mnew) * 0.125f);
      float p11 = __expf((st1[1] - mnew) * 0.125f);
      float p12 = __expf((st1[2] - mnew) * 0.125f);
      float p13 = __expf((st1[3] - mnew) * 0.125f);
      float psum = ((p00 + p01) + (p02 + p03)) + ((p10 + p11) + (p12 + p13));
      psum += __shfl_xor(psum, 16);
      psum += __shfl_xor(psum, 32);
      // pack P pairs: pk[kf][w] holds k = kf*16 + grp*4 + {2w, 2w+1}
      int pk00 = (int)pack_bf2(p00, p01), pk01 = (int)pack_bf2(p02, p03);
      int pk10 = (int)pack_bf2(p10, p11), pk11 = (int)pack_bf2(p12, p13);
      // redistribute to A-frag: lane needs k = grp*8 + e (e=0..7)
      int a0 = __shfl(pk00, srcA), a1 = __shfl(pk10, srcA);
      int b0 = __shfl(pk01, srcA), b1 = __shfl(pk11, srcA);
      int c0 = __shfl(pk00, srcB), c1 = __shfl(pk10, srcB);
      int d0 = __shfl(pk01, srcB), d1 = __shfl(pk11, srcB);
      u32x4 pu;
      pu[0] = (unsigned int)((grp < 2) ? a0 : a1);
      pu[1] = (unsigned int)((grp < 2) ? b0 : b1);
      pu[2] = (unsigned int)((grp < 2) ? c0 : c1);
      pu[3] = (unsigned int)((grp < 2) ? d0 : d1);
      s16x8 pa = __builtin_bit_cast(s16x8, pu);
      // rescale running state + accumulator
      const float fac = __expf((m_st[f] - mnew) * 0.125f);
      l_st[f] = l_st[f] * fac + psum;
      m_st[f] = mnew;
      float fr[4];
      #pragma unroll
      for (int r = 0; r < 4; ++r) fr[r] = __shfl(fac, grp * 4 + r);
      #pragma unroll
      for (int dn = 0; dn < 4; ++dn)
        #pragma unroll
        for (int r = 0; r < 4; ++r) acc[f][dn][r] *= fr[r];
      #pragma unroll
      for (int dn = 0; dn < 4; ++dn)
        acc[f][dn] = __builtin_amdgcn_mfma_f32_16x16x32_bf16(pa, vfr[dn], acc[f][dn], 0, 0, 0);
    }
  };

  for (int kt = 0; kt < nkt; kt += 2) {
    int kb1 = (kt + 1 < nkt) ? (kt + 1) * 32 : kt * 32;
    LOADK(kB, kb1);
    body(kA, kt);
    if (kt + 1 >= nkt) break;
    int kb2 = (kt + 2 < nkt) ? (kt + 2) * 32 : (kt + 1) * 32;
    LOADK(kA, kb2);
    body(kB, kt + 1);
  }
#undef LOADK

  #pragma unroll
  for (int f = 0; f < 2; ++f) {
    float linv[4];
    #pragma unroll
    for (int r = 0; r < 4; ++r) linv[r] = 1.f / __shfl(l_st[f], grp * 4 + r);
    #pragma unroll
    for (int dn = 0; dn < 4; ++dn)
      #pragma unroll
      for (int r = 0; r < 4; ++r) {
        int row = b * SEQ_ + qbase + f * 16 + grp * 4 + r;
        ctx[(size_t)row * 2048 + h * 64 + dn * 16 + l15] = f2bf(acc[f][dn][r] * linv[r]);
      }
  }
}

extern "C" void kernel_launch(void* const* d_in, const int* in_sizes, int n_in,
                              void* d_out, int out_size, void* d_ws, size_t ws_size,
                              hipStream_t stream) {
  const float* x  = (const float*)d_in[0];
  const float* cs = (const float*)d_in[2];
  const float* sn = (const float*)d_in[3];
  const float* Wq = (const float*)d_in[4];
  const float* Wk = (const float*)d_in[5];
  const float* Wv = (const float*)d_in[6];
  const float* Wo = (const float*)d_in[7];
  const float* qs = (const float*)d_in[8];
  const float* ks = (const float*)d_in[9];
  float* out = (float*)d_out;

  unsigned short* xb  = (unsigned short*)d_ws;
  unsigned short* Wt  = xb  + (size_t)4096 * 2048;
  unsigned short* Wot = Wt  + (size_t)3072 * 2048;
  unsigned short* qkv = Wot + (size_t)2048 * 2048;
  unsigned short* vTb = qkv + (size_t)4096 * 3072;
  unsigned short* ctx = vTb + (size_t)16 * 64 * 2048;

  cvtx<<<4096, 256, 0, stream>>>(x, xb);
  wtrans<<<dim3(32, 32), 256, 0, stream>>>(Wq, Wt, 2048);
  wtrans<<<dim3(8, 32),  256, 0, stream>>>(Wk, Wt + (size_t)2048 * 2048, 512);
  wtrans<<<dim3(8, 32),  256, 0, stream>>>(Wv, Wt + (size_t)2560 * 2048, 512);
  wtrans<<<dim3(32, 32), 256, 0, stream>>>(Wo, Wot, 2048);
  gemm_bt<1><<<dim3(24, 32), 256, 0, stream>>>(xb, Wt, qkv, 3072);
  rmsrope<<<dim3(1024, 32), 256, 0, stream>>>(qkv, qs, cs, sn, 0);
  rmsrope<<<dim3(1024, 8),  256, 0, stream>>>(qkv, ks, cs, sn, 2048);
  vtrans<<<dim3(32, 16), 256, 0, stream>>>(qkv, vTb);
  attn_mfma2<<<1024, 256, 0, stream>>>(qkv, vTb, ctx);
  gemm_bt<0><<<dim3(16, 32), 256, 0, stream>>>(ctx, Wot, out, 2048);
}

// Round 5
// 290.273 us; speedup vs baseline: 8.6981x; 1.1144x over previous
//
#include <hip/hip_runtime.h>
#include <hip/hip_bf16.h>
#include <cstdint>
#include <cstddef>

#define EMB   2048
#define NH_   32
#define NG_   8
#define DH_   64
#define SEQ_  2048
#define BB_   2
#define MTOT  4096
#define LDQKV 3072

typedef __attribute__((ext_vector_type(8))) short s16x8;
typedef __attribute__((ext_vector_type(8))) unsigned short u16x8;
typedef __attribute__((ext_vector_type(4))) float f32x4;
typedef __attribute__((ext_vector_type(16))) float f32x16;
typedef __attribute__((ext_vector_type(4))) unsigned int u32x4;
typedef __attribute__((ext_vector_type(2))) unsigned int u32x2;
typedef __attribute__((ext_vector_type(2))) int i32x2;

__device__ __forceinline__ float bf2f(unsigned short u) {
  unsigned int x = (unsigned int)u << 16; return __uint_as_float(x);
}
__device__ __forceinline__ unsigned short f2bf(float f) {
  unsigned int x = __float_as_uint(f);
  x = x + 0x7FFFu + ((x >> 16) & 1u);          // RNE
  return (unsigned short)(x >> 16);
}
__device__ __forceinline__ float ninf() { return __int_as_float(0xff800000); }
__device__ __forceinline__ unsigned int pack_bf2(float a, float b) {
  unsigned int r;
  asm("v_cvt_pk_bf16_f32 %0, %1, %2" : "=v"(r) : "v"(a), "v"(b));
  return r;
}
// lane i (<32) half of a stays; a.hi <- b.lo ; b.lo <- a.hi ; b.hi stays.
__device__ __forceinline__ void plswap(unsigned int& a, unsigned int& b) {
  i32x2 r = __builtin_amdgcn_permlane32_swap((int)a, (int)b, false, false);
  a = (unsigned int)r[0]; b = (unsigned int)r[1];
}
__device__ __forceinline__ void plswapf(float& a, float& b) {
  unsigned int ua = __float_as_uint(a), ub = __float_as_uint(b);
  plswap(ua, ub);
  a = __uint_as_float(ua); b = __uint_as_float(ub);
}

__device__ __forceinline__ void glds16(const void* g, void* l) {
  __builtin_amdgcn_global_load_lds((const __attribute__((address_space(1))) void*)g,
                                   (__attribute__((address_space(3))) void*)l, 16, 0, 0);
}

// ---------- x f32 -> bf16 ----------
__global__ __launch_bounds__(256)
void cvtx(const float* __restrict__ x, unsigned short* __restrict__ xb) {
  size_t i = (size_t)blockIdx.x * 256 + threadIdx.x;
  float4 a = *(const float4*)(x + i * 8);
  float4 c = *(const float4*)(x + i * 8 + 4);
  u16x8 o;
  o[0] = f2bf(a.x); o[1] = f2bf(a.y); o[2] = f2bf(a.z); o[3] = f2bf(a.w);
  o[4] = f2bf(c.x); o[5] = f2bf(c.y); o[6] = f2bf(c.z); o[7] = f2bf(c.w);
  *(u16x8*)(xb + i * 8) = o;
}

// ---------- W[K=2048][N] f32 -> Wt[N][2048] bf16 ----------
__global__ __launch_bounds__(256)
void wtrans(const float* __restrict__ in, unsigned short* __restrict__ out, int N) {
  __shared__ float tile[64][65];
  const int tid = threadIdx.x;
  const int n0 = blockIdx.x * 64, k0 = blockIdx.y * 64;
  #pragma unroll
  for (int jj = 0; jj < 4; ++jj) {
    int r = (tid >> 4) + jj * 16;
    int c = (tid & 15) * 4;
    float4 v = *(const float4*)(in + (size_t)(k0 + r) * N + n0 + c);
    tile[r][c] = v.x; tile[r][c + 1] = v.y; tile[r][c + 2] = v.z; tile[r][c + 3] = v.w;
  }
  __syncthreads();
  #pragma unroll
  for (int rep = 0; rep < 2; ++rep) {
    int u = rep * 256 + tid;
    int nl = u >> 3, ch = u & 7;
    u16x8 o;
    #pragma unroll
    for (int e = 0; e < 8; ++e) o[e] = f2bf(tile[ch * 8 + e][nl]);
    *(u16x8*)(out + (size_t)(n0 + nl) * 2048 + k0 + ch * 8) = o;
  }
}

// ---------- MFMA GEMM: C[M,N] = A[M,2048] @ Bt[N,2048]^T ; BM=BN=128, BK=32 ----------
template<int BF16OUT>
__global__ __launch_bounds__(256)
void gemm_bt(const unsigned short* __restrict__ A, const unsigned short* __restrict__ Bt,
             void* __restrict__ C, int ldc) {
  __shared__ __align__(16) unsigned short As[128 * 32];
  __shared__ __align__(16) unsigned short Bs[128 * 32];
  const int tid = threadIdx.x;
  const int w = tid >> 6, lane = tid & 63;
  const int grp = lane >> 4, l15 = lane & 15;
  const int wr = w >> 1, wc = w & 1;
  const int bm = blockIdx.y * 128, bn = blockIdx.x * 128;
  f32x4 acc[4][4] = {};
  for (int k0 = 0; k0 < 2048; k0 += 32) {
    #pragma unroll
    for (int j = 0; j < 2; ++j) {
      int unit = (j * 4 + w) * 64 + lane;
      int row = unit >> 2, ch = unit & 3;
      glds16(A  + (size_t)(bm + row) * 2048 + k0 + ch * 8, (char*)As + (j * 4 + w) * 1024);
      glds16(Bt + (size_t)(bn + row) * 2048 + k0 + ch * 8, (char*)Bs + (j * 4 + w) * 1024);
    }
    __syncthreads();
    s16x8 af[4], bf[4];
    #pragma unroll
    for (int i = 0; i < 4; ++i)
      af[i] = *(const s16x8*)((const char*)As + (wr * 64 + i * 16 + l15) * 64 + grp * 16);
    #pragma unroll
    for (int j = 0; j < 4; ++j)
      bf[j] = *(const s16x8*)((const char*)Bs + (wc * 64 + j * 16 + l15) * 64 + grp * 16);
    #pragma unroll
    for (int i = 0; i < 4; ++i)
      #pragma unroll
      for (int j = 0; j < 4; ++j)
        acc[i][j] = __builtin_amdgcn_mfma_f32_16x16x32_bf16(af[i], bf[j], acc[i][j], 0, 0, 0);
    __syncthreads();
  }
  #pragma unroll
  for (int i = 0; i < 4; ++i)
    #pragma unroll
    for (int j = 0; j < 4; ++j)
      #pragma unroll
      for (int r = 0; r < 4; ++r) {
        int row = bm + wr * 64 + i * 16 + grp * 4 + r;
        int col = bn + wc * 64 + j * 16 + l15;
        float v = acc[i][j][r];
        if (BF16OUT) ((unsigned short*)C)[(size_t)row * ldc + col] = f2bf(v);
        else         ((float*)C)[(size_t)row * ldc + col] = v;
      }
}

// ---------- fused RMSNorm(D=64) + RoPE, in-place bf16; optional post-scale ----------
__global__ __launch_bounds__(256)
void rmsrope(unsigned short* __restrict__ t, const float* __restrict__ scale,
             const float* __restrict__ cs, const float* __restrict__ sn, int coff, float post) {
  int m = blockIdx.x * 4 + (threadIdx.x >> 6);
  int h = blockIdx.y;
  int lane = threadIdx.x & 63;
  int spos = m & (SEQ_ - 1);
  unsigned short* p = t + (size_t)m * LDQKV + coff + h * 64 + lane;
  float val = bf2f(*p);
  float sq = val * val;
  #pragma unroll
  for (int off = 32; off; off >>= 1) sq += __shfl_xor(sq, off);
  float r = rsqrtf(sq * (1.f / 64.f) + 1e-6f);
  float xn = val * r * scale[lane];
  float partner = __shfl_xor(xn, 32);
  float c = cs[spos * 64 + lane], s = sn[spos * 64 + lane];
  float o = (lane < 32) ? (xn * c - partner * s) : fmaf(xn, c, partner * s);
  *p = f2bf(o * post);
}

// ---------- v region of qkv -> vT[(b*8+g)*64 + d][s] bf16 ----------
__global__ __launch_bounds__(256)
void vtrans(const unsigned short* __restrict__ qkv, unsigned short* __restrict__ vT) {
  __shared__ unsigned short tile[64][72];
  const int tid = threadIdx.x;
  const int st = blockIdx.x;
  const int bg = blockIdx.y;
  const int b = bg >> 3, g = bg & 7;
  #pragma unroll
  for (int rep = 0; rep < 2; ++rep) {
    int u = rep * 256 + tid;
    int sl = u >> 3, ch = u & 7;
    u16x8 v = *(const u16x8*)(qkv + (size_t)(b * SEQ_ + st * 64 + sl) * LDQKV + 2560 + g * 64 + ch * 8);
    #pragma unroll
    for (int e = 0; e < 8; ++e) tile[sl][ch * 8 + e] = v[e];
  }
  __syncthreads();
  #pragma unroll
  for (int rep = 0; rep < 2; ++rep) {
    int u = rep * 256 + tid;
    int d = u >> 3, ch = u & 7;
    u16x8 o;
    #pragma unroll
    for (int e = 0; e < 8; ++e) o[e] = tile[ch * 8 + e][d];
    *(u16x8*)(vT + (size_t)(bg * 64 + d) * SEQ_ + st * 64 + ch * 8) = o;
  }
}

// ---------- MFMA flash attention v3: 32x32 frags, zero cross-lane softmax ----------
// One wave = 32 q-rows per tile, two tiles {63-idx, idx} (uniform 65 k-iterations).
// S^T = mfma32(K,Q): C col = lane&31 = q, so m/l/fac/linv are lane-local with
// the O^T accumulator. k-reduce & P redistribution via permlane32_swap (VALU).
// Q pre-scaled by 0.125*log2e in rmsrope -> exp2f directly.
__global__ __launch_bounds__(256)
void attn_mfma3(const unsigned short* __restrict__ qkv, const unsigned short* __restrict__ vT,
                unsigned short* __restrict__ ctx) {
  const int tid = threadIdx.x;
  const int w = tid >> 6, lane = tid & 63;
  const int l31 = lane & 31, half = lane >> 5;
  const int bid = blockIdx.x;
  const int bh = bid >> 3, blk8 = bid & 7;
  const int b = bh >> 5, h = bh & 31, g = h >> 2;
  const int idx = blk8 * 4 + w;                 // 0..31

  const unsigned short* qp = qkv + (size_t)(b * SEQ_ + l31) * LDQKV + h * 64 + half * 8;
  const unsigned short* kp = qkv + (size_t)(b * SEQ_ + l31) * LDQKV + 2048 + g * 64 + half * 8;
  const unsigned short* vp = vT + (size_t)((b * NG_ + g) * 64 + l31) * SEQ_ + half * 8;

  #pragma unroll 1
  for (int ti = 0; ti < 2; ++ti) {
    const int qt = ti ? idx : (63 - idx);
    const int qbase = qt * 32;
    const int nkt = qt + 1;

    s16x8 qf[4];
    #pragma unroll
    for (int s = 0; s < 4; ++s)
      qf[s] = *(const s16x8*)(qp + (size_t)qbase * LDQKV + s * 16);

    f32x16 acc0 = {}, acc1 = {};
    float m_st = ninf(), l_st = 0.f;

    auto loadk = [&](s16x8 (&KF)[4], int kb) {
      #pragma unroll
      for (int s = 0; s < 4; ++s)
        KF[s] = *(const s16x8*)(kp + (size_t)kb * LDQKV + s * 16);
    };

    auto body = [&](const s16x8 (&KF)[4], int kt_) {
      const int kbase = kt_ * 32;
      // V fragments for this k-tile (issued first, consumed after softmax)
      s16x8 vf00 = *(const s16x8*)(vp + kbase);
      s16x8 vf01 = *(const s16x8*)(vp + kbase + 16);
      s16x8 vf10 = *(const s16x8*)(vp + (size_t)32 * SEQ_ + kbase);
      s16x8 vf11 = *(const s16x8*)(vp + (size_t)32 * SEQ_ + kbase + 16);
      f32x16 st = {};
      #pragma unroll
      for (int s = 0; s < 4; ++s)
        st = __builtin_amdgcn_mfma_f32_32x32x16_bf16(KF[s], qf[s], st, 0, 0, 0);
      if (kt_ == qt) {                         // mask key > q (kbase == qbase)
        #pragma unroll
        for (int r = 0; r < 16; ++r) {
          int key = (r & 3) + 8 * (r >> 2) + 4 * half;
          if (key > l31) st[r] = ninf();
        }
      }
      // max over k: 15 local fmax + cross-half swap
      float t8[8];
      #pragma unroll
      for (int r = 0; r < 8; ++r) t8[r] = fmaxf(st[r], st[r + 8]);
      float t4a = fmaxf(t8[0], t8[1]), t4b = fmaxf(t8[2], t8[3]);
      float t4c = fmaxf(t8[4], t8[5]), t4d = fmaxf(t8[6], t8[7]);
      float pm = fmaxf(fmaxf(t4a, t4b), fmaxf(t4c, t4d));
      { float a = pm, bsw = pm; plswapf(a, bsw); pm = fmaxf(a, bsw); }
      const float mnew = fmaxf(m_st, pm);
      if (__any(pm > m_st)) {                  // rescale only when max grew
        const float fac = exp2f(m_st - mnew);
        l_st *= fac;
        #pragma unroll
        for (int r = 0; r < 16; ++r) { acc0[r] *= fac; acc1[r] *= fac; }
        m_st = mnew;
      }
      float p[16];
      #pragma unroll
      for (int r = 0; r < 16; ++r) p[r] = exp2f(st[r] - m_st);
      float s8[8];
      #pragma unroll
      for (int r = 0; r < 8; ++r) s8[r] = p[r] + p[r + 8];
      float s4a = s8[0] + s8[1], s4b = s8[2] + s8[3];
      float s4c = s8[4] + s8[5], s4d = s8[6] + s8[7];
      float psum = (s4a + s4b) + (s4c + s4d);
      { float a = psum, bsw = psum; plswapf(a, bsw); psum = a + bsw; }
      l_st += psum;
      // pack P -> bf16 pairs; permlane-swap into PV B-fragments
      unsigned int PK[8];
      #pragma unroll
      for (int j = 0; j < 8; ++j) PK[j] = pack_bf2(p[2 * j], p[2 * j + 1]);
      plswap(PK[0], PK[2]); plswap(PK[1], PK[3]);
      plswap(PK[4], PK[6]); plswap(PK[5], PK[7]);
      u32x4 pb0u, pb1u;
      pb0u[0] = PK[0]; pb0u[1] = PK[1]; pb0u[2] = PK[2]; pb0u[3] = PK[3];
      pb1u[0] = PK[4]; pb1u[1] = PK[5]; pb1u[2] = PK[6]; pb1u[3] = PK[7];
      s16x8 pb0 = __builtin_bit_cast(s16x8, pb0u);
      s16x8 pb1 = __builtin_bit_cast(s16x8, pb1u);
      acc0 = __builtin_amdgcn_mfma_f32_32x32x16_bf16(vf00, pb0, acc0, 0, 0, 0);
      acc0 = __builtin_amdgcn_mfma_f32_32x32x16_bf16(vf01, pb1, acc0, 0, 0, 0);
      acc1 = __builtin_amdgcn_mfma_f32_32x32x16_bf16(vf10, pb0, acc1, 0, 0, 0);
      acc1 = __builtin_amdgcn_mfma_f32_32x32x16_bf16(vf11, pb1, acc1, 0, 0, 0);
    };

    s16x8 kA[4], kB[4];
    loadk(kA, 0);
    for (int kt = 0; kt < nkt; kt += 2) {
      loadk(kB, (kt + 1 < nkt) ? (kt + 1) * 32 : kt * 32);
      body(kA, kt);
      if (kt + 1 >= nkt) break;
      loadk(kA, (kt + 2 < nkt) ? (kt + 2) * 32 : (kt + 1) * 32);
      body(kB, kt + 1);
    }

    const float linv = 1.f / l_st;
    unsigned short* orow = ctx + (size_t)(b * SEQ_ + qbase + l31) * 2048 + h * 64;
    #pragma unroll
    for (int dt = 0; dt < 2; ++dt) {
      #pragma unroll
      for (int rq = 0; rq < 4; ++rq) {
        const int r = rq * 4;
        const int d0 = dt * 32 + 8 * rq + 4 * half;
        float a0 = (dt ? acc1[r]     : acc0[r])     * linv;
        float a1 = (dt ? acc1[r + 1] : acc0[r + 1]) * linv;
        float a2 = (dt ? acc1[r + 2] : acc0[r + 2]) * linv;
        float a3 = (dt ? acc1[r + 3] : acc0[r + 3]) * linv;
        u32x2 o;
        o[0] = pack_bf2(a0, a1);
        o[1] = pack_bf2(a2, a3);
        *(u32x2*)(orow + d0) = o;
      }
    }
  }
}

extern "C" void kernel_launch(void* const* d_in, const int* in_sizes, int n_in,
                              void* d_out, int out_size, void* d_ws, size_t ws_size,
                              hipStream_t stream) {
  const float* x  = (const float*)d_in[0];
  const float* cs = (const float*)d_in[2];
  const float* sn = (const float*)d_in[3];
  const float* Wq = (const float*)d_in[4];
  const float* Wk = (const float*)d_in[5];
  const float* Wv = (const float*)d_in[6];
  const float* Wo = (const float*)d_in[7];
  const float* qs = (const float*)d_in[8];
  const float* ks = (const float*)d_in[9];
  float* out = (float*)d_out;

  unsigned short* xb  = (unsigned short*)d_ws;
  unsigned short* Wt  = xb  + (size_t)4096 * 2048;
  unsigned short* Wot = Wt  + (size_t)3072 * 2048;
  unsigned short* qkv = Wot + (size_t)2048 * 2048;
  unsigned short* vTb = qkv + (size_t)4096 * 3072;
  unsigned short* ctx = vTb + (size_t)16 * 64 * 2048;

  cvtx<<<4096, 256, 0, stream>>>(x, xb);
  wtrans<<<dim3(32, 32), 256, 0, stream>>>(Wq, Wt, 2048);
  wtrans<<<dim3(8, 32),  256, 0, stream>>>(Wk, Wt + (size_t)2048 * 2048, 512);
  wtrans<<<dim3(8, 32),  256, 0, stream>>>(Wv, Wt + (size_t)2560 * 2048, 512);
  wtrans<<<dim3(32, 32), 256, 0, stream>>>(Wo, Wot, 2048);
  gemm_bt<1><<<dim3(24, 32), 256, 0, stream>>>(xb, Wt, qkv, 3072);
  rmsrope<<<dim3(1024, 32), 256, 0, stream>>>(qkv, qs, cs, sn, 0, 0.18033688f);
  rmsrope<<<dim3(1024, 8),  256, 0, stream>>>(qkv, ks, cs, sn, 2048, 1.0f);
  vtrans<<<dim3(32, 16), 256, 0, stream>>>(qkv, vTb);
  attn_mfma3<<<512, 256, 0, stream>>>(qkv, vTb, ctx);
  gemm_bt<0><<<dim3(16, 32), 256, 0, stream>>>(ctx, Wot, out, 2048);
}